// Round 1
// baseline (281.903 us; speedup 1.0000x reference)
//
#include <hip/hip_runtime.h>
#include <math.h>

// ---------------------------------------------------------------------------
// LTFGW: N=4096 nodes, K=16 neighbors (k1=17), T=16 templates, NT=16, D=128
// OUTER=3, INNER=5.
//
// Mapping (main kernel): 1 block / node, 256 threads = 16 templates x 16 cols.
// All 17x16 per-(n,t) matrices are column-distributed over 16 lanes (one DPP
// row). Cross-lane matmul vs C2^T via DPP XOR-walk (VALU pipe). C1 via scalar
// (s_load) reads from a pre-gathered workspace. M via precomputed P = x@tf^T.
// ---------------------------------------------------------------------------

#define NN 4096
#define DD 128
#define KNB 16
#define K1 17
#define TT 16
#define NTT 16
#define C1STRIDE 20   // 17 floats C1 row + cc1 at [17] + pad
#define C1NODE 340    // 17*20

typedef const __attribute__((address_space(4))) float* c4fp;
typedef const __attribute__((address_space(4))) int*   c4ip;

__device__ __forceinline__ float sload(const float* p) {
  return *(c4fp)(unsigned long long)p;
}
__device__ __forceinline__ int sloadi(const int* p) {
  return *(c4ip)(unsigned long long)p;
}

template<int CTRL>
__device__ __forceinline__ float dppmov(float x) {
  return __int_as_float(
      __builtin_amdgcn_update_dpp(0, __float_as_int(x), CTRL, 0xF, 0xF, true));
}
// xor4 = half_mirror(xor7) then quad_perm[3,2,1,0](xor3)
__device__ __forceinline__ float xor4v(float x) {
  return dppmov<0x1B>(dppmov<0x141>(x));
}
__device__ __forceinline__ float rsum16(float x) {
  x += dppmov<0xB1>(x);   // xor1
  x += dppmov<0x4E>(x);   // xor2
  x += xor4v(x);          // xor4
  x += dppmov<0x128>(x);  // xor8 (row_ror:8)
  return x;
}
__device__ __forceinline__ float rmin16(float x) {
  x = fminf(x, dppmov<0xB1>(x));
  x = fminf(x, dppmov<0x4E>(x));
  x = fminf(x, xor4v(x));
  x = fminf(x, dppmov<0x128>(x));
  return x;
}
__device__ __forceinline__ float rmax16(float x) {
  x = fmaxf(x, dppmov<0xB1>(x));
  x = fmaxf(x, dppmov<0x4E>(x));
  x = fmaxf(x, xor4v(x));
  x = fmaxf(x, dppmov<0x128>(x));
  return x;
}

// DPP XOR-walk over cumulative masks 0..15; deltas 1,3,1,7,1,3,1,15,...
#define WSTEP(C, R) { g = dppmov<C>(g); acc = fmaf(g, c2reg[R], acc); }
#define WALK15() \
  WSTEP(0xB1,1)  WSTEP(0x1B,2)  WSTEP(0xB1,3)  WSTEP(0x141,4) \
  WSTEP(0xB1,5)  WSTEP(0x1B,6)  WSTEP(0xB1,7)  WSTEP(0x140,8) \
  WSTEP(0xB1,9)  WSTEP(0x1B,10) WSTEP(0xB1,11) WSTEP(0x141,12) \
  WSTEP(0xB1,13) WSTEP(0x1B,14) WSTEP(0xB1,15)

// ---------------------------------------------------------------------------
// prep_small: alpha, q=softmax(q0), cq[t][l]=sum_m q[t,m]*C2[t,l,m]^2,
//             tfsq[tm]=||tf_tm||^2.   1 block x 256 threads.
// ---------------------------------------------------------------------------
__global__ void prep_small(const float* __restrict__ q0,
                           const float* __restrict__ templates_,
                           const float* __restrict__ tf,
                           const float* __restrict__ alpha0,
                           float* __restrict__ qmat, float* __restrict__ cq,
                           float* __restrict__ tfsq, float* __restrict__ walpha) {
  int tid = threadIdx.x;
  int t = tid >> 4, l = tid & 15;
  if (tid == 0) walpha[0] = 1.f / (1.f + expf(-alpha0[0]));
  float qr[16];
  float mx = -3.0e38f;
#pragma unroll
  for (int m = 0; m < 16; ++m) { qr[m] = q0[t*16 + m]; mx = fmaxf(mx, qr[m]); }
  float s = 0.f;
#pragma unroll
  for (int m = 0; m < 16; ++m) { qr[m] = expf(qr[m] - mx); s += qr[m]; }
  float inv = 1.f / s;
  qmat[tid] = qr[l] * inv;
  float c = 0.f;
#pragma unroll
  for (int m = 0; m < 16; ++m) {
    float c2 = templates_[t*256 + l*16 + m];
    c = fmaf(qr[m] * inv, c2 * c2, c);
  }
  cq[tid] = c;
  float ts = 0.f;
#pragma unroll
  for (int dq = 0; dq < 32; ++dq) {
    float4 v = *(const float4*)&tf[tid*128 + dq*4];
    ts = fmaf(v.x, v.x, ts); ts = fmaf(v.y, v.y, ts);
    ts = fmaf(v.z, v.z, ts); ts = fmaf(v.w, v.w, ts);
  }
  tfsq[tid] = ts;
}

// ---------------------------------------------------------------------------
// xsq_kernel: xsq[n] = ||x[n]||^2. 1 wave per row; 4 rows per 256-thr block.
// ---------------------------------------------------------------------------
__global__ void xsq_kernel(const float* __restrict__ x, float* __restrict__ xsq) {
  int n = blockIdx.x * 4 + (threadIdx.x >> 6);
  int lane = threadIdx.x & 63;
  float2 v = *(const float2*)&x[n*128 + lane*2];
  float s = fmaf(v.x, v.x, v.y * v.y);
  s += __shfl_xor(s, 1);  s += __shfl_xor(s, 2);  s += __shfl_xor(s, 4);
  s += __shfl_xor(s, 8);  s += __shfl_xor(s, 16); s += __shfl_xor(s, 32);
  if (lane == 0) xsq[n] = s;
}

// ---------------------------------------------------------------------------
// pgemm: P(4096x256) = x(4096x128) @ tf^T(128x256). 64x64 tiles, 4x4/thread.
// ---------------------------------------------------------------------------
__global__ __launch_bounds__(256, 2) void pgemm(const float* __restrict__ x,
                                                const float* __restrict__ tf,
                                                float* __restrict__ P) {
  __shared__ __align__(16) float As[64][68];  // As[d][row]
  __shared__ __align__(16) float Bs[64][68];  // Bs[d][col]
  int tid = threadIdx.x;
  int tx = tid & 15, ty = tid >> 4;
  int r0 = blockIdx.x * 64, c0 = blockIdx.y * 64;
  float acc[4][4] = {};
  for (int h = 0; h < 2; ++h) {
    __syncthreads();
#pragma unroll
    for (int q = 0; q < 4; ++q) {
      int f = tid + 256*q;          // 1024 float4 = 64 rows x 64 d
      int row = f >> 4;
      int d4 = (f & 15) << 2;
      float4 a = *(const float4*)&x[(r0+row)*128 + h*64 + d4];
      As[d4+0][row] = a.x; As[d4+1][row] = a.y;
      As[d4+2][row] = a.z; As[d4+3][row] = a.w;
      float4 b = *(const float4*)&tf[(c0+row)*128 + h*64 + d4];
      Bs[d4+0][row] = b.x; Bs[d4+1][row] = b.y;
      Bs[d4+2][row] = b.z; Bs[d4+3][row] = b.w;
    }
    __syncthreads();
#pragma unroll
    for (int d = 0; d < 64; ++d) {
      float4 a = *(const float4*)&As[d][ty*4];
      float4 b = *(const float4*)&Bs[d][tx*4];
      float av[4] = {a.x, a.y, a.z, a.w};
      float bv[4] = {b.x, b.y, b.z, b.w};
#pragma unroll
      for (int i = 0; i < 4; ++i)
#pragma unroll
        for (int j = 0; j < 4; ++j) acc[i][j] = fmaf(av[i], bv[j], acc[i][j]);
    }
  }
#pragma unroll
  for (int i = 0; i < 4; ++i) {
    float4 o; o.x = acc[i][0]; o.y = acc[i][1]; o.z = acc[i][2]; o.w = acc[i][3];
    *(float4*)&P[(r0 + ty*4 + i)*256 + c0 + tx*4] = o;
  }
}

// ---------------------------------------------------------------------------
// c1gather: C1ws[n][i][0..16] = adj[nb_i, nb_j]; C1ws[n][i][17] = cc1_i.
// ---------------------------------------------------------------------------
__global__ __launch_bounds__(320) void c1gather(const float* __restrict__ adj,
                                                const int* __restrict__ neighbors,
                                                float* __restrict__ C1ws) {
  __shared__ int nbs[K1];
  __shared__ float c1sh[K1 * K1];
  int n = blockIdx.x;
  int tid = threadIdx.x;
  if (tid < K1) nbs[tid] = (tid == 0) ? n : neighbors[n*KNB + tid - 1];
  __syncthreads();
  if (tid < 289) {
    int i = tid / 17, j = tid % 17;
    float v = adj[nbs[i]*NN + nbs[j]];
    C1ws[n*C1NODE + i*C1STRIDE + j] = v;
    c1sh[tid] = v;
  }
  __syncthreads();
  if (tid < K1) {
    float s = 0.f;
#pragma unroll
    for (int j = 0; j < K1; ++j) { float v = c1sh[tid*17 + j]; s = fmaf(v, v, s); }
    C1ws[n*C1NODE + tid*C1STRIDE + 17] = s * (1.f/17.f);
  }
}

// ---------------------------------------------------------------------------
// main kernel
// ---------------------------------------------------------------------------
__global__ __launch_bounds__(256, 2) void ltfgw_main(
    const float* __restrict__ P, const float* __restrict__ C1ws,
    const float* __restrict__ xsq, const float* __restrict__ tfsq,
    const float* __restrict__ qmat, const float* __restrict__ cq,
    const float* __restrict__ walpha, const int* __restrict__ neighbors,
    const float* __restrict__ templates_, float* __restrict__ out) {
  __shared__ __align__(16) float Ksh[16 * 292];  // per-t K matrix, row stride 17
  __shared__ __align__(16) float Ush[256];
  __shared__ __align__(16) float Vsh[256];

  const int tid = threadIdx.x;
  const int t = tid >> 4, l = tid & 15;
  const int n = blockIdx.x;

  const float alpha = sload(walpha);
  const float oma = 1.f - alpha;
  const float na2 = -2.f * alpha;

  int nbk[K1];
  nbk[0] = n;
#pragma unroll
  for (int k = 1; k < K1; ++k) nbk[k] = sloadi(neighbors + n*KNB + (k-1));

  const float tfsq_l = tfsq[tid];
  const float cq_l = cq[tid];
  const float q_l = qmat[tid];

  // Mcol = (1-a)*M + a*cC  (pre-blended)
  float Mcol[K1];
#pragma unroll
  for (int k = 0; k < K1; ++k) {
    float xs  = sload(xsq + nbk[k]);
    float cc1 = sload(C1ws + n*C1NODE + k*C1STRIDE + 17);
    float pv  = P[nbk[k]*256 + tid];
    Mcol[k] = oma * (xs + tfsq_l - 2.f*pv) + alpha * (cc1 + cq_l);
  }

  // c2reg[r] = -2a * C2[t][l][l^r]  (pre-rotated for the XOR walk)
  float c2reg[16];
#pragma unroll
  for (int r = 0; r < 16; ++r)
    c2reg[r] = na2 * templates_[t*256 + l*16 + (l ^ r)];

  float Gcol[K1];
#pragma unroll
  for (int k = 0; k < K1; ++k) Gcol[k] = (1.f/17.f) * q_l;

  const int tb = t * 292;

#pragma unroll 1
  for (int outer = 0; outer < 3; ++outer) {
    // T1 = C1 @ G : lane-local matvec, C1 via scalar loads
    float T1[K1];
#pragma unroll
    for (int i = 0; i < K1; ++i) {
      const float* c1r = C1ws + n*C1NODE + i*C1STRIDE;
      float s = 0.f;
#pragma unroll
      for (int j = 0; j < K1; ++j) s = fmaf(sload(c1r + j), Gcol[j], s);
      T1[i] = s;
    }
    // grad = Mcol + na2*(T1 @ C2^T) via DPP walk; track lo/hi
    float Kc[K1];
    float lo = 3.0e38f, hi = -3.0e38f;
#pragma unroll
    for (int i = 0; i < K1; ++i) {
      float g = T1[i];
      float acc = g * c2reg[0];
      WALK15()
      float gr = Mcol[i] + acc;
      Kc[i] = gr;
      lo = fminf(lo, gr); hi = fmaxf(hi, gr);
    }
    lo = rmin16(lo); hi = rmax16(hi);
    float eps = 0.1f * (hi - lo) + 1e-16f;
    float sc = 1.4426950408889634f * __builtin_amdgcn_rcpf(eps);
#pragma unroll
    for (int i = 0; i < K1; ++i) Kc[i] = exp2f((lo - Kc[i]) * sc);

    // transpose K (within-wave, no barrier needed)
#pragma unroll
    for (int k = 0; k < K1; ++k) Ksh[tb + k*17 + l] = Kc[k];
    float Krow[16], kr16[16];
#pragma unroll
    for (int j = 0; j < 16; ++j) Krow[j] = Ksh[tb + l*17 + j];
#pragma unroll
    for (int jq = 0; jq < 4; ++jq) {
      float4 v = *(const float4*)&Ksh[tb + 272 + jq*4];
      kr16[jq*4+0] = v.x; kr16[jq*4+1] = v.y;
      kr16[jq*4+2] = v.z; kr16[jq*4+3] = v.w;
    }

    // Sinkhorn: 5 iters, u-first, v0 = 1
    float ur[16];
    float u16 = 0.f, vm = 1.f;
    Vsh[tid] = 1.f;
#pragma unroll 1
    for (int it = 0; it < 5; ++it) {
      float vr[16];
#pragma unroll
      for (int q = 0; q < 4; ++q) {
        float4 v = *(const float4*)&Vsh[t*16 + q*4];
        vr[q*4+0] = v.x; vr[q*4+1] = v.y; vr[q*4+2] = v.z; vr[q*4+3] = v.w;
      }
      float w = 0.f, w16 = 0.f;
#pragma unroll
      for (int j = 0; j < 16; ++j) {
        w   = fmaf(Krow[j], vr[j], w);
        w16 = fmaf(kr16[j], vr[j], w16);
      }
      float um = (1.f/17.f) * __builtin_amdgcn_rcpf(fmaxf(w,   1e-16f));
      u16      = (1.f/17.f) * __builtin_amdgcn_rcpf(fmaxf(w16, 1e-16f));
      Ush[tid] = um;
#pragma unroll
      for (int q = 0; q < 4; ++q) {
        float4 v = *(const float4*)&Ush[t*16 + q*4];
        ur[q*4+0] = v.x; ur[q*4+1] = v.y; ur[q*4+2] = v.z; ur[q*4+3] = v.w;
      }
      float sg = u16 * Kc[16];
#pragma unroll
      for (int k = 0; k < 16; ++k) sg = fmaf(ur[k], Kc[k], sg);
      vm = q_l * __builtin_amdgcn_rcpf(fmaxf(sg, 1e-16f));
      Vsh[tid] = vm;
    }
    // G = u * K * v
#pragma unroll
    for (int k = 0; k < 16; ++k) Gcol[k] = ur[k] * Kc[k] * vm;
    Gcol[16] = u16 * Kc[16] * vm;
  }

  // final: out[n,t] = sum_{i,l} (Mcol + na2*T2) * G
  float T1[K1];
#pragma unroll
  for (int i = 0; i < K1; ++i) {
    const float* c1r = C1ws + n*C1NODE + i*C1STRIDE;
    float s = 0.f;
#pragma unroll
    for (int j = 0; j < K1; ++j) s = fmaf(sload(c1r + j), Gcol[j], s);
    T1[i] = s;
  }
  float accout = 0.f;
#pragma unroll
  for (int i = 0; i < K1; ++i) {
    float g = T1[i];
    float acc = g * c2reg[0];
    WALK15()
    accout = fmaf(Mcol[i] + acc, Gcol[i], accout);
  }
  accout = rsum16(accout);
  if (l == 0) out[n*TT + t] = accout;
}

// ---------------------------------------------------------------------------
extern "C" void kernel_launch(void* const* d_in, const int* in_sizes, int n_in,
                              void* d_out, int out_size, void* d_ws, size_t ws_size,
                              hipStream_t stream) {
  const float* x          = (const float*)d_in[0];
  const float* adj        = (const float*)d_in[1];
  const int*   neighbors  = (const int*)  d_in[2];
  const float* templates_ = (const float*)d_in[3];
  const float* tfeat      = (const float*)d_in[4];
  const float* q0         = (const float*)d_in[5];
  const float* alpha0     = (const float*)d_in[6];
  float* out = (float*)d_out;

  float* ws     = (float*)d_ws;
  float* P      = ws;                       // 4096*256
  float* C1ws   = P + 4096*256;             // 4096*340
  float* xsq    = C1ws + 4096*C1NODE;       // 4096
  float* tfsq   = xsq + 4096;               // 256
  float* qmat   = tfsq + 256;               // 256
  float* cq     = qmat + 256;               // 256
  float* walpha = cq + 256;                 // 1

  hipLaunchKernelGGL(prep_small, dim3(1), dim3(256), 0, stream,
                     q0, templates_, tfeat, alpha0, qmat, cq, tfsq, walpha);
  hipLaunchKernelGGL(xsq_kernel, dim3(1024), dim3(256), 0, stream, x, xsq);
  hipLaunchKernelGGL(pgemm, dim3(64, 4), dim3(256), 0, stream, x, tfeat, P);
  hipLaunchKernelGGL(c1gather, dim3(4096), dim3(320), 0, stream,
                     adj, neighbors, C1ws);
  hipLaunchKernelGGL(ltfgw_main, dim3(4096), dim3(256), 0, stream,
                     P, C1ws, xsq, tfsq, qmat, cq, walpha, neighbors,
                     templates_, out);
}